// Round 1
// baseline (1491.774 us; speedup 1.0000x reference)
//
#include <hip/hip_runtime.h>
#include <hip/hip_bf16.h>

// Kuramoto V2: B=8, N=2048, D=256, 50 steps.
// Strategy:
//  1) normalize embeddings (wave per row)
//  2) build C = clip(En @ En^T, 0) once  [B,N,N] fp32 (134 MB in d_ws)
//  3) 50x step kernel: two matvecs (C*cos(theta), C*sin(theta)) via
//     sin(ti-tj) = sin(ti)cos(tj) - cos(ti)sin(tj), then Euler + fmod.

constexpr int B = 8;
constexpr int N = 2048;
constexpr int D = 256;
constexpr float DT = 0.01f;
constexpr float K_OVER_N = 1.0f / 2048.0f;
constexpr float TWO_PI_F = 6.2831854820251465f; // float(2*pi), matches np.float32

// ---------------- normalize: one wave (64 lanes) per row of 256 floats ----
__global__ void normalize_k(const float* __restrict__ emb, float* __restrict__ En) {
    int row  = blockIdx.x * 4 + (threadIdx.x >> 6);   // 4 waves per block
    int lane = threadIdx.x & 63;
    const float4 v = *(const float4*)(emb + (size_t)row * D + lane * 4);
    float ss = v.x * v.x + v.y * v.y + v.z * v.z + v.w * v.w;
    #pragma unroll
    for (int k = 32; k >= 1; k >>= 1) ss += __shfl_xor(ss, k);
    float inv = 1.0f / fmaxf(sqrtf(ss), 1e-12f);
    float4 o = {v.x * inv, v.y * inv, v.z * inv, v.w * inv};
    *(float4*)(En + (size_t)row * D + lane * 4) = o;
}

// ---------------- build C = clip(En En^T, 0): 64x64 tile, 4x4 per thread ---
constexpr int BT = 64;  // output tile side
constexpr int BK = 16;  // k-chunk
constexpr int LDP = 68; // padded LDS stride (2-way bank alias = free, keeps 16B align)

__global__ __launch_bounds__(256) void build_c_k(const float* __restrict__ En,
                                                 float* __restrict__ C) {
    __shared__ float As[BK][LDP];
    __shared__ float Bs[BK][LDP];
    const int b  = blockIdx.z;
    const int i0 = blockIdx.y * BT;
    const int j0 = blockIdx.x * BT;
    const float* Eb = En + (size_t)b * N * D;

    const int tid  = threadIdx.x;
    const int tx   = tid & 15;        // 0..15 -> j micro
    const int ty   = tid >> 4;        // 0..15 -> i micro
    const int lrow = tid >> 2;        // 0..63 row within tile for loads
    const int lk4  = (tid & 3) * 4;   // 0,4,8,12 k-offset for float4 load

    float acc[4][4] = {};

    for (int k0 = 0; k0 < D; k0 += BK) {
        float4 a = *(const float4*)(Eb + (size_t)(i0 + lrow) * D + k0 + lk4);
        float4 bb = *(const float4*)(Eb + (size_t)(j0 + lrow) * D + k0 + lk4);
        __syncthreads();
        As[lk4 + 0][lrow] = a.x;  As[lk4 + 1][lrow] = a.y;
        As[lk4 + 2][lrow] = a.z;  As[lk4 + 3][lrow] = a.w;
        Bs[lk4 + 0][lrow] = bb.x; Bs[lk4 + 1][lrow] = bb.y;
        Bs[lk4 + 2][lrow] = bb.z; Bs[lk4 + 3][lrow] = bb.w;
        __syncthreads();
        #pragma unroll
        for (int k = 0; k < BK; ++k) {
            const float4 av = *(const float4*)&As[k][ty * 4];
            const float4 bv = *(const float4*)&Bs[k][tx * 4];
            const float aa[4] = {av.x, av.y, av.z, av.w};
            const float bbv[4] = {bv.x, bv.y, bv.z, bv.w};
            #pragma unroll
            for (int ii = 0; ii < 4; ++ii)
                #pragma unroll
                for (int jj = 0; jj < 4; ++jj)
                    acc[ii][jj] = fmaf(aa[ii], bbv[jj], acc[ii][jj]);
        }
    }

    float* Cb = C + (size_t)b * N * N;
    #pragma unroll
    for (int ii = 0; ii < 4; ++ii) {
        float4 o = {fmaxf(acc[ii][0], 0.f), fmaxf(acc[ii][1], 0.f),
                    fmaxf(acc[ii][2], 0.f), fmaxf(acc[ii][3], 0.f)};
        *(float4*)(Cb + (size_t)(i0 + ty * 4 + ii) * N + j0 + tx * 4) = o;
    }
}

// ---------------- one Euler step: 16 rows/block (4 waves x 4 rows) ---------
__global__ __launch_bounds__(256) void step_k(const float* __restrict__ Cm,
                                              const float* __restrict__ tin,
                                              float* __restrict__ tout,
                                              const float* __restrict__ omega) {
    __shared__ float s_sin[N];
    __shared__ float s_cos[N];
    const int b = blockIdx.y;
    const float* th = tin + (size_t)b * N;

    for (int j = threadIdx.x; j < N; j += 256) {
        float s, c;
        sincosf(th[j], &s, &c);
        s_sin[j] = s;
        s_cos[j] = c;
    }
    __syncthreads();

    const int wave = threadIdx.x >> 6;
    const int lane = threadIdx.x & 63;
    const float* Cb = Cm + (size_t)b * N * N;
    const int rowbase = blockIdx.x * 16 + wave * 4;

    for (int r = 0; r < 4; ++r) {
        const int i = rowbase + r;
        const float4* crow = (const float4*)(Cb + (size_t)i * N);
        float s1 = 0.f, s2 = 0.f;  // sum C*cos, sum C*sin
        #pragma unroll
        for (int it = 0; it < 8; ++it) {
            const int j4 = it * 64 + lane;
            const float4 c  = crow[j4];
            const float4 sc = *(const float4*)&s_cos[j4 * 4];
            const float4 sn = *(const float4*)&s_sin[j4 * 4];
            s1 = fmaf(c.x, sc.x, s1); s1 = fmaf(c.y, sc.y, s1);
            s1 = fmaf(c.z, sc.z, s1); s1 = fmaf(c.w, sc.w, s1);
            s2 = fmaf(c.x, sn.x, s2); s2 = fmaf(c.y, sn.y, s2);
            s2 = fmaf(c.z, sn.z, s2); s2 = fmaf(c.w, sn.w, s2);
        }
        #pragma unroll
        for (int k = 32; k >= 1; k >>= 1) {
            s1 += __shfl_xor(s1, k);
            s2 += __shfl_xor(s2, k);
        }
        if (lane == 0) {
            const float ti = th[i];
            const float csum = s_sin[i] * s1 - s_cos[i] * s2;
            const float dth = omega[i] + K_OVER_N * csum;
            tout[(size_t)b * N + i] = fmodf(ti + DT * dth, TWO_PI_F);
        }
    }
}

extern "C" void kernel_launch(void* const* d_in, const int* in_sizes, int n_in,
                              void* d_out, int out_size, void* d_ws, size_t ws_size,
                              hipStream_t stream) {
    const float* theta0 = (const float*)d_in[0];  // [B,N]
    const float* emb    = (const float*)d_in[1];  // [B,N,D]
    const float* omega  = (const float*)d_in[2];  // [N]
    float* out = (float*)d_out;                   // [B,N]

    // workspace layout (needs ~145 MiB)
    float* En   = (float*)d_ws;                   // B*N*D
    float* C    = En + (size_t)B * N * D;         // B*N*N
    float* buf0 = C + (size_t)B * N * N;          // B*N
    float* buf1 = buf0 + (size_t)B * N;           // B*N

    normalize_k<<<B * N / 4, 256, 0, stream>>>(emb, En);

    dim3 gC(N / BT, N / BT, B);
    build_c_k<<<gC, 256, 0, stream>>>(En, C);

    float* bufs[2] = {buf0, buf1};
    for (int s = 0; s < 50; ++s) {
        const float* tin = (s == 0) ? theta0 : bufs[s & 1];
        float* tout = (s == 49) ? out : bufs[(s + 1) & 1];
        step_k<<<dim3(N / 16, B), 256, 0, stream>>>(C, tin, tout, omega);
    }
}

// Round 2
// 756.132 us; speedup vs baseline: 1.9729x; 1.9729x over previous
//
#include <hip/hip_runtime.h>
#include <hip/hip_bf16.h>

// Kuramoto V2: B=8, N=2048, D=256, 50 steps.
//  1) normalize embeddings -> bf16 En
//  2) C = clip(En En^T, 0) as bf16 via MFMA (built once, 67 MB, L3-resident)
//  3) 50x step: csum_i = sin(ti)*(C·cos)_i - cos(ti)*(C·sin)_i using
//     ping-ponged packed-bf16 cos/sin tables written by the previous step.

constexpr int B = 8;
constexpr int N = 2048;
constexpr int D = 256;
constexpr float DT = 0.01f;
constexpr float K_OVER_N = 1.0f / 2048.0f;
constexpr float TWO_PI_F = 6.2831854820251465f; // float(2*pi)

using bf16x8 = __attribute__((ext_vector_type(8))) short;
using f32x4  = __attribute__((ext_vector_type(4))) float;

static __device__ __forceinline__ unsigned short f2bf(float f) {
    union { float f; unsigned int i; } v; v.f = f;
    unsigned int x = v.i;
    x += 0x7fffu + ((x >> 16) & 1u);   // RNE
    return (unsigned short)(x >> 16);
}
static __device__ __forceinline__ float bfbits_lo(unsigned int u) {
    union { unsigned int i; float f; } v; v.i = u << 16; return v.f;
}
static __device__ __forceinline__ float bfbits_hi(unsigned int u) {
    union { unsigned int i; float f; } v; v.i = u & 0xffff0000u; return v.f;
}

// ---------------- normalize: one wave per row of 256 floats -> bf16 -------
__global__ void normalize_k(const float* __restrict__ emb,
                            unsigned short* __restrict__ En) {
    const int row  = blockIdx.x * 4 + (threadIdx.x >> 6);
    const int lane = threadIdx.x & 63;
    const float4 v = *(const float4*)(emb + (size_t)row * D + lane * 4);
    float ss = v.x * v.x + v.y * v.y + v.z * v.z + v.w * v.w;
    #pragma unroll
    for (int k = 32; k >= 1; k >>= 1) ss += __shfl_xor(ss, k);
    const float inv = 1.0f / fmaxf(sqrtf(ss), 1e-12f);
    ushort4 o;
    o.x = f2bf(v.x * inv); o.y = f2bf(v.y * inv);
    o.z = f2bf(v.z * inv); o.w = f2bf(v.w * inv);
    *(ushort4*)(En + (size_t)row * D + lane * 4) = o;
}

// ---------------- build C = clip(En En^T, 0) via bf16 MFMA -----------------
// Block = 4 waves, 128x128 output; each wave 64x64 (4x4 tiles of 16x16x32).
// A-frag: row = i_base+m*16+(lane&15), k = k0+(lane>>4)*8 + 0..7
// B-frag (B = En^T): col = j_base+n*16+(lane&15), same k  -> same load pattern.
// C/D:    col = lane&15, row = (lane>>4)*4 + reg   [m89-verified]
__global__ __launch_bounds__(256) void build_c_k(const unsigned short* __restrict__ En,
                                                 unsigned short* __restrict__ C) {
    const int b = blockIdx.z;
    const unsigned short* Eb = En + (size_t)b * N * D;
    const int wid  = threadIdx.x >> 6;
    const int lane = threadIdx.x & 63;
    const int i_base = blockIdx.y * 128 + (wid >> 1) * 64;
    const int j_base = blockIdx.x * 128 + (wid & 1) * 64;
    const int fr = lane & 15;
    const int fk = (lane >> 4) * 8;

    f32x4 acc[4][4];
    #pragma unroll
    for (int m = 0; m < 4; ++m)
        #pragma unroll
        for (int n = 0; n < 4; ++n)
            acc[m][n] = (f32x4){0.f, 0.f, 0.f, 0.f};

    for (int k0 = 0; k0 < D; k0 += 32) {
        bf16x8 a[4], bv[4];
        #pragma unroll
        for (int m = 0; m < 4; ++m)
            a[m] = *(const bf16x8*)(Eb + (size_t)(i_base + m * 16 + fr) * D + k0 + fk);
        #pragma unroll
        for (int n = 0; n < 4; ++n)
            bv[n] = *(const bf16x8*)(Eb + (size_t)(j_base + n * 16 + fr) * D + k0 + fk);
        #pragma unroll
        for (int m = 0; m < 4; ++m)
            #pragma unroll
            for (int n = 0; n < 4; ++n)
                acc[m][n] = __builtin_amdgcn_mfma_f32_16x16x32_bf16(a[m], bv[n], acc[m][n], 0, 0, 0);
    }

    unsigned short* Cb = C + (size_t)b * N * N;
    const int orow = (lane >> 4) * 4;
    #pragma unroll
    for (int m = 0; m < 4; ++m)
        #pragma unroll
        for (int n = 0; n < 4; ++n)
            #pragma unroll
            for (int r = 0; r < 4; ++r)
                Cb[(size_t)(i_base + m * 16 + orow + r) * N + j_base + n * 16 + fr] =
                    f2bf(fmaxf(acc[m][n][r], 0.f));
}

// ---------------- init tables: packed {cos,sin} bf16 of theta0 -------------
__global__ void init_tbl_k(const float* __restrict__ theta,
                           unsigned int* __restrict__ tbl) {
    const int idx = blockIdx.x * 256 + threadIdx.x;
    float s, c;
    sincosf(theta[idx], &s, &c);
    tbl[idx] = (unsigned int)f2bf(c) | ((unsigned int)f2bf(s) << 16);
}

// ---------------- one Euler step: 16 rows/block (4 waves x 4 rows) ---------
__global__ __launch_bounds__(256) void step_k(const unsigned short* __restrict__ Cm,
                                              const unsigned int* __restrict__ tbl_in,
                                              unsigned int* __restrict__ tbl_out,
                                              const float* __restrict__ tin,
                                              float* __restrict__ tout,
                                              const float* __restrict__ omega) {
    __shared__ unsigned short s_cos[N];   // bf16 tables, contiguous -> 16B/lane
    __shared__ unsigned short s_sin[N];   // ds_read_b128 conflict-free
    const int b = blockIdx.y;
    #pragma unroll
    for (int t = 0; t < 8; ++t) {
        const int j = t * 256 + threadIdx.x;
        const unsigned int p = tbl_in[(size_t)b * N + j];
        s_cos[j] = (unsigned short)(p & 0xffffu);
        s_sin[j] = (unsigned short)(p >> 16);
    }
    __syncthreads();

    const int wave = threadIdx.x >> 6;
    const int lane = threadIdx.x & 63;
    const int rowbase = blockIdx.x * 16 + wave * 4;

    #pragma unroll
    for (int r = 0; r < 4; ++r) {
        const int i = rowbase + r;
        const unsigned short* crow = Cm + ((size_t)b * N + i) * N;
        float s1 = 0.f, s2 = 0.f;   // sum C*cos, sum C*sin
        #pragma unroll
        for (int it = 0; it < 4; ++it) {
            const int j0 = it * 512 + lane * 8;              // 8 bf16 per lane
            const uint4 cw = *(const uint4*)(crow + j0);     // 16B coalesced
            const uint4 pc = *(const uint4*)(s_cos + j0);
            const uint4 ps = *(const uint4*)(s_sin + j0);
            const unsigned int cu[4]  = {cw.x, cw.y, cw.z, cw.w};
            const unsigned int ccu[4] = {pc.x, pc.y, pc.z, pc.w};
            const unsigned int ssu[4] = {ps.x, ps.y, ps.z, ps.w};
            #pragma unroll
            for (int q = 0; q < 4; ++q) {
                const float c0 = bfbits_lo(cu[q]),  c1 = bfbits_hi(cu[q]);
                const float k0 = bfbits_lo(ccu[q]), k1 = bfbits_hi(ccu[q]);
                const float n0 = bfbits_lo(ssu[q]), n1 = bfbits_hi(ssu[q]);
                s1 = fmaf(c0, k0, s1); s1 = fmaf(c1, k1, s1);
                s2 = fmaf(c0, n0, s2); s2 = fmaf(c1, n1, s2);
            }
        }
        #pragma unroll
        for (int k = 32; k >= 1; k >>= 1) {
            s1 += __shfl_xor(s1, k);
            s2 += __shfl_xor(s2, k);
        }
        if (lane == 0) {
            const float ti = tin[(size_t)b * N + i];
            float si, ci;
            sincosf(ti, &si, &ci);               // fp32 on the i-side
            const float csum = si * s1 - ci * s2;
            const float th = fmodf(ti + DT * (omega[i] + K_OVER_N * csum), TWO_PI_F);
            tout[(size_t)b * N + i] = th;
            float sn, cn;
            sincosf(th, &sn, &cn);               // table for next step
            tbl_out[(size_t)b * N + i] = (unsigned int)f2bf(cn) | ((unsigned int)f2bf(sn) << 16);
        }
    }
}

extern "C" void kernel_launch(void* const* d_in, const int* in_sizes, int n_in,
                              void* d_out, int out_size, void* d_ws, size_t ws_size,
                              hipStream_t stream) {
    const float* theta0 = (const float*)d_in[0];  // [B,N]
    const float* emb    = (const float*)d_in[1];  // [B,N,D]
    const float* omega  = (const float*)d_in[2];  // [N]
    float* out = (float*)d_out;                   // [B,N]

    // workspace layout (~76 MiB)
    unsigned short* En  = (unsigned short*)d_ws;             // B*N*D bf16 (8 MB)
    unsigned short* C   = En + (size_t)B * N * D;            // B*N*N bf16 (67 MB)
    unsigned int*   tb0 = (unsigned int*)(C + (size_t)B * N * N); // B*N
    unsigned int*   tb1 = tb0 + (size_t)B * N;               // B*N
    float* buf0 = (float*)(tb1 + (size_t)B * N);             // B*N
    float* buf1 = buf0 + (size_t)B * N;                      // B*N

    normalize_k<<<B * N / 4, 256, 0, stream>>>(emb, En);

    dim3 gC(N / 128, N / 128, B);
    build_c_k<<<gC, 256, 0, stream>>>(En, C);

    init_tbl_k<<<B * N / 256, 256, 0, stream>>>(theta0, tb0);

    unsigned int* tbls[2] = {tb0, tb1};
    float* bufs[2] = {buf0, buf1};
    for (int s = 0; s < 50; ++s) {
        const float* tin = (s == 0) ? theta0 : bufs[s & 1];
        float* tout = (s == 49) ? out : bufs[(s + 1) & 1];
        step_k<<<dim3(N / 16, B), 256, 0, stream>>>(C, tbls[s & 1], tbls[(s + 1) & 1],
                                                    tin, tout, omega);
    }
}

// Round 3
// 568.137 us; speedup vs baseline: 2.6257x; 1.3309x over previous
//
#include <hip/hip_runtime.h>
#include <hip/hip_bf16.h>

// Kuramoto V2: B=8, N=2048, D=256, 50 steps.
//  1) normalize embeddings -> bf16 En
//  2) C = clip(En En^T, 0) -> fp8 e4m3, row-major, via bf16 MFMA.
//     C is exactly symmetric, so the column-grouped C/D fragment (4 rows x
//     1 col per thread) is stored TRANSPOSED as a packed u32 -> row-major.
//  3) 50x step: csum_i = sin(ti)*(C cos)_i - cos(ti)*(C sin)_i.
//     Dual matvec via mfma_f32_16x16x32_fp8_fp8 with B = [cos|sin|0...],
//     fp8 cos/sin tables ping-ponged in global, staged to LDS per block.

constexpr int B = 8;
constexpr int N = 2048;
constexpr int D = 256;
constexpr float DT = 0.01f;
constexpr float K_OVER_N = 1.0f / 2048.0f;
constexpr float TWO_PI_F = 6.2831854820251465f; // float(2*pi)

using bf16x8 = __attribute__((ext_vector_type(8))) short;
using f32x4  = __attribute__((ext_vector_type(4))) float;

static __device__ __forceinline__ unsigned short f2bf(float f) {
    union { float f; unsigned int i; } v; v.f = f;
    unsigned int x = v.i;
    x += 0x7fffu + ((x >> 16) & 1u);   // RNE
    return (unsigned short)(x >> 16);
}
static __device__ __forceinline__ unsigned char f2fp8(float f) {
    return (unsigned char)(__builtin_amdgcn_cvt_pk_fp8_f32(f, f, 0, false) & 0xff);
}

// ---------------- normalize: one wave per row of 256 floats -> bf16 -------
__global__ void normalize_k(const float* __restrict__ emb,
                            unsigned short* __restrict__ En) {
    const int row  = blockIdx.x * 4 + (threadIdx.x >> 6);
    const int lane = threadIdx.x & 63;
    const float4 v = *(const float4*)(emb + (size_t)row * D + lane * 4);
    float ss = v.x * v.x + v.y * v.y + v.z * v.z + v.w * v.w;
    #pragma unroll
    for (int k = 32; k >= 1; k >>= 1) ss += __shfl_xor(ss, k);
    const float inv = 1.0f / fmaxf(sqrtf(ss), 1e-12f);
    ushort4 o;
    o.x = f2bf(v.x * inv); o.y = f2bf(v.y * inv);
    o.z = f2bf(v.z * inv); o.w = f2bf(v.w * inv);
    *(ushort4*)(En + (size_t)row * D + lane * 4) = o;
}

// ---------------- build C = clip(En En^T, 0) -> fp8 row-major --------------
// A-frag: row = i_base+m*16+(lane&15), k = (lane>>4)*8 + 0..7  [r2-verified]
// C/D:    col = lane&15, row = (lane>>4)*4 + reg               [m89]
// Thread's 4 regs = 4 consecutive rows, one col j -> pack u32, store at
// C[j][i..i+3] (valid because C == C^T bitwise).
__global__ __launch_bounds__(256) void build_c_k(const unsigned short* __restrict__ En,
                                                 unsigned char* __restrict__ C) {
    const int b = blockIdx.z;
    const unsigned short* Eb = En + (size_t)b * N * D;
    const int wid  = threadIdx.x >> 6;
    const int lane = threadIdx.x & 63;
    const int i_base = blockIdx.y * 128 + (wid >> 1) * 64;
    const int j_base = blockIdx.x * 128 + (wid & 1) * 64;
    const int fr = lane & 15;
    const int fk = (lane >> 4) * 8;

    f32x4 acc[4][4];
    #pragma unroll
    for (int m = 0; m < 4; ++m)
        #pragma unroll
        for (int n = 0; n < 4; ++n)
            acc[m][n] = (f32x4){0.f, 0.f, 0.f, 0.f};

    for (int k0 = 0; k0 < D; k0 += 32) {
        bf16x8 a[4], bv[4];
        #pragma unroll
        for (int m = 0; m < 4; ++m)
            a[m] = *(const bf16x8*)(Eb + (size_t)(i_base + m * 16 + fr) * D + k0 + fk);
        #pragma unroll
        for (int n = 0; n < 4; ++n)
            bv[n] = *(const bf16x8*)(Eb + (size_t)(j_base + n * 16 + fr) * D + k0 + fk);
        #pragma unroll
        for (int m = 0; m < 4; ++m)
            #pragma unroll
            for (int n = 0; n < 4; ++n)
                acc[m][n] = __builtin_amdgcn_mfma_f32_16x16x32_bf16(a[m], bv[n], acc[m][n], 0, 0, 0);
    }

    unsigned char* Cb = C + (size_t)b * N * N;
    const int orow = (lane >> 4) * 4;
    #pragma unroll
    for (int m = 0; m < 4; ++m)
        #pragma unroll
        for (int n = 0; n < 4; ++n) {
            int w = __builtin_amdgcn_cvt_pk_fp8_f32(fmaxf(acc[m][n][0], 0.f),
                                                    fmaxf(acc[m][n][1], 0.f), 0, false);
            w = __builtin_amdgcn_cvt_pk_fp8_f32(fmaxf(acc[m][n][2], 0.f),
                                                fmaxf(acc[m][n][3], 0.f), w, true);
            const int j = j_base + n * 16 + fr;
            const int i = i_base + m * 16 + orow;
            *(unsigned int*)(Cb + (size_t)j * N + i) = (unsigned int)w;
        }
}

// ---------------- init tables: fp8 cos/sin of theta0 -----------------------
__global__ void init_tbl_k(const float* __restrict__ theta,
                           unsigned char* __restrict__ cosT,
                           unsigned char* __restrict__ sinT) {
    const int idx = blockIdx.x * 256 + threadIdx.x;
    float s, c;
    sincosf(theta[idx], &s, &c);
    cosT[idx] = f2fp8(c);
    sinT[idx] = f2fp8(s);
}

// ---------------- one Euler step: 1 block = 16 rows, 4 waves K-split -------
__global__ __launch_bounds__(256) void step_k(const unsigned char* __restrict__ C,
                                              const unsigned char* __restrict__ cosI,
                                              const unsigned char* __restrict__ sinI,
                                              unsigned char* __restrict__ cosO,
                                              unsigned char* __restrict__ sinO,
                                              const float* __restrict__ tin,
                                              float* __restrict__ tout,
                                              const float* __restrict__ omega) {
    __shared__ alignas(16) unsigned char s_tbl[2048 + 32 + 2048]; // cos | pad | sin
    __shared__ f32x4 s_acc[4][8];   // [wave][g*2+col] (col 0=cos-sum, 1=sin-sum)
    const int rt = blockIdx.x;      // 16-row tile
    const int b  = blockIdx.y;
    const int t  = threadIdx.x;

    if (t < 128)
        *(uint4*)(s_tbl + t * 16) = *(const uint4*)(cosI + (size_t)b * N + t * 16);
    else
        *(uint4*)(s_tbl + 2080 + (t - 128) * 16) = *(const uint4*)(sinI + (size_t)b * N + (t - 128) * 16);
    __syncthreads();

    const int w    = t >> 6;
    const int lane = t & 63;
    const int col  = lane & 15;     // A-row / D-col selector
    const int g    = lane >> 4;     // k-subgroup
    // A: row-major fp8 C, row = rt*16 + col, k-chunk = this wave's quarter
    const unsigned char* Ap = C + ((size_t)b * N + rt * 16 + col) * N + g * 8 + w * 512;
    // B: col 0 -> cos table, col 1 -> sin table, cols >=2 zeroed
    const unsigned char* Bp = s_tbl + ((col == 1) ? 2080 : 0) + g * 8 + w * 512;

    f32x4 acc = {0.f, 0.f, 0.f, 0.f};
    #pragma unroll
    for (int u = 0; u < 16; ++u) {
        const long a  = *(const long*)(Ap + u * 32);
        long bv = *(const long*)(Bp + u * 32);
        bv = (col < 2) ? bv : 0L;
        acc = __builtin_amdgcn_mfma_f32_16x16x32_fp8_fp8(a, bv, acc, 0, 0, 0);
    }
    if (col < 2) s_acc[w][g * 2 + col] = acc;
    __syncthreads();

    if (t < 16) {                   // finalize row i = rt*16 + t
        const int gg = (t >> 2) * 2, rr = t & 3;
        float S1 = 0.f, S2 = 0.f;
        #pragma unroll
        for (int ww = 0; ww < 4; ++ww) {
            S1 += s_acc[ww][gg + 0][rr];
            S2 += s_acc[ww][gg + 1][rr];
        }
        const int i = rt * 16 + t;
        const size_t bi = (size_t)b * N + i;
        const float ti = tin[bi];
        float si, ci;
        sincosf(ti, &si, &ci);
        const float csum = si * S1 - ci * S2;
        const float th = fmodf(ti + DT * (omega[i] + K_OVER_N * csum), TWO_PI_F);
        tout[bi] = th;
        float sn, cn;
        sincosf(th, &sn, &cn);
        cosO[bi] = f2fp8(cn);
        sinO[bi] = f2fp8(sn);
    }
}

extern "C" void kernel_launch(void* const* d_in, const int* in_sizes, int n_in,
                              void* d_out, int out_size, void* d_ws, size_t ws_size,
                              hipStream_t stream) {
    const float* theta0 = (const float*)d_in[0];  // [B,N]
    const float* emb    = (const float*)d_in[1];  // [B,N,D]
    const float* omega  = (const float*)d_in[2];  // [N]
    float* out = (float*)d_out;                   // [B,N]

    // workspace layout (~42 MiB)
    unsigned short* En = (unsigned short*)d_ws;                    // B*N*D bf16
    unsigned char*  C  = (unsigned char*)(En + (size_t)B * N * D); // B*N*N fp8
    unsigned char* ct0 = C + (size_t)B * N * N;                    // B*N fp8
    unsigned char* ct1 = ct0 + (size_t)B * N;
    unsigned char* st0 = ct1 + (size_t)B * N;
    unsigned char* st1 = st0 + (size_t)B * N;
    float* buf0 = (float*)(st1 + (size_t)B * N);                   // B*N f32
    float* buf1 = buf0 + (size_t)B * N;

    normalize_k<<<B * N / 4, 256, 0, stream>>>(emb, En);

    dim3 gC(N / 128, N / 128, B);
    build_c_k<<<gC, 256, 0, stream>>>(En, C);

    init_tbl_k<<<B * N / 256, 256, 0, stream>>>(theta0, ct0, st0);

    unsigned char* cT[2] = {ct0, ct1};
    unsigned char* sT[2] = {st0, st1};
    float* bufs[2] = {buf0, buf1};
    for (int s = 0; s < 50; ++s) {
        const float* tin = (s == 0) ? theta0 : bufs[s & 1];
        float* tout = (s == 49) ? out : bufs[(s + 1) & 1];
        step_k<<<dim3(N / 16, B), 256, 0, stream>>>(C, cT[s & 1], sT[s & 1],
                                                    cT[(s + 1) & 1], sT[(s + 1) & 1],
                                                    tin, tout, omega);
    }
}